// Round 6
// baseline (914.934 us; speedup 1.0000x reference)
//
#include <hip/hip_runtime.h>
#include <cstddef>
#include <cstdint>

#define D_DIM 2048
#define S_DIM 4096
#define B_DIM 4
#define M_DIM (B_DIM * S_DIM)   // 16384
#define N1_DIM (3 * D_DIM)      // 6144
#define CHUNK 16                // s-rows per conv block

typedef short bf16x8 __attribute__((ext_vector_type(8)));
typedef float f32x4  __attribute__((ext_vector_type(4)));

typedef const unsigned int __attribute__((address_space(1))) gu32_t;
typedef unsigned int       __attribute__((address_space(3))) lu32_t;

__device__ __forceinline__ unsigned short f2bf(float f) {
    unsigned int u = __float_as_uint(f);
    u += 0x7FFFu + ((u >> 16) & 1u);   // round-to-nearest-even (finite inputs)
    return (unsigned short)(u >> 16);
}
__device__ __forceinline__ float bf2f(unsigned short h) {
    return __uint_as_float(((unsigned int)h) << 16);
}

// ---------- fp32 -> bf16 straight convert (8 elems/thread) ----------
__global__ void k_convert(const float* __restrict__ in, unsigned short* __restrict__ out, int n8) {
    int i = blockIdx.x * blockDim.x + threadIdx.x;
    if (i >= n8) return;
    const float4* p = (const float4*)in + (size_t)i * 2;
    float4 a = p[0];
    float4 b = p[1];
    union { unsigned short s[8]; uint4 v; } r;
    r.s[0] = f2bf(a.x); r.s[1] = f2bf(a.y); r.s[2] = f2bf(a.z); r.s[3] = f2bf(a.w);
    r.s[4] = f2bf(b.x); r.s[5] = f2bf(b.y); r.s[6] = f2bf(b.z); r.s[7] = f2bf(b.w);
    ((uint4*)out)[i] = r.v;
}

// ---------- fp32 (R x C) -> bf16 transposed (C x R) ----------
__global__ void k_transpose(const float* __restrict__ in, unsigned short* __restrict__ out,
                            int R, int C) {
    __shared__ float t[32][33];
    int c0 = blockIdx.x * 32, r0 = blockIdx.y * 32;
    int x = threadIdx.x;
    for (int yy = threadIdx.y; yy < 32; yy += 8)
        t[yy][x] = in[(size_t)(r0 + yy) * C + c0 + x];
    __syncthreads();
    for (int yy = threadIdx.y; yy < 32; yy += 8)
        out[(size_t)(c0 + yy) * R + r0 + x] = f2bf(t[x][yy]);
}

// ---------- bf16 GEMM: C[M,N] = A[M,K] * Bt[N,K]^T (proven 128^2 kernel) ----------
// 128x128 tile, BK=64, 4 waves (2x2), each wave 64x64 via 4x4 of 16x16x32 MFMA.
// Staging: global_load_lds width=16, XOR-swizzled source granules so the
// contiguous LDS destination still yields conflict-free ds_read_b128.
// R5: XCD-chunked block swizzle (T1). HW round-robins linear block id
// across the 8 XCDs; remapping id -> (id&7)*cpx + (id>>3) gives each XCD a
// CONTIGUOUS run of tiles, so blocks sharing an A-panel (consecutive ids,
// n-tile fastest) co-reside on one XCD's L2 instead of refilling 8 L2s.
template <bool OUT_BF16>
__global__ __launch_bounds__(256, 2)
void k_gemm128(const unsigned short* __restrict__ A, const unsigned short* __restrict__ Bt,
               void* __restrict__ Cp, int N, int K) {
    __shared__ unsigned short As[128 * 64];
    __shared__ unsigned short Bs[128 * 64];

    const int tid  = threadIdx.x;
    const int wave = tid >> 6;
    const int lane = tid & 63;

    // XCD-chunked swizzle (bijective: grid size is a multiple of 8 here)
    const int nbx = gridDim.x;
    const int nwg = nbx * gridDim.y;
    const int cpx = nwg >> 3;
    const int id  = blockIdx.y * nbx + blockIdx.x;
    const int swz = (id & 7) * cpx + (id >> 3);
    const int m0 = (swz / nbx) * 128;
    const int n0 = (swz % nbx) * 128;

    const int wm = (wave & 1) * 64;
    const int wn = (wave >> 1) * 64;

    f32x4 acc[4][4] = {};

    const int srow = lane >> 3;
    const int gd   = lane & 7;
    const int quad = lane >> 4;
    const int rsel = lane & 15;

    const int KT = K >> 6;
    for (int kt = 0; kt < KT; ++kt) {
        const int k0 = kt << 6;
        __syncthreads();
        #pragma unroll
        for (int i = 0; i < 4; ++i) {
            const int seg = i * 4 + wave;
            const int row = seg * 8 + srow;
            const int gs  = gd ^ (row & 7);
            const unsigned short* ga = A  + (size_t)(m0 + row) * K + k0 + gs * 8;
            const unsigned short* gb = Bt + (size_t)(n0 + row) * K + k0 + gs * 8;
            __builtin_amdgcn_global_load_lds((gu32_t*)ga, (lu32_t*)(As + seg * 512), 16, 0, 0);
            __builtin_amdgcn_global_load_lds((gu32_t*)gb, (lu32_t*)(Bs + seg * 512), 16, 0, 0);
        }
        __syncthreads();

        #pragma unroll
        for (int kb = 0; kb < 2; ++kb) {
            bf16x8 af[4], bfr[4];
            #pragma unroll
            for (int i = 0; i < 4; ++i) {
                const int ra = wm + i * 16 + rsel;
                const int ga = (kb * 4 + quad) ^ (ra & 7);
                af[i] = *(const bf16x8*)&As[ra * 64 + ga * 8];
                const int rb = wn + i * 16 + rsel;
                const int gb = (kb * 4 + quad) ^ (rb & 7);
                bfr[i] = *(const bf16x8*)&Bs[rb * 64 + gb * 8];
            }
            #pragma unroll
            for (int i = 0; i < 4; ++i)
                #pragma unroll
                for (int j = 0; j < 4; ++j)
                    acc[i][j] = __builtin_amdgcn_mfma_f32_16x16x32_bf16(af[i], bfr[j], acc[i][j], 0, 0, 0);
        }
    }

    // Epilogue: C/D layout col=lane&15, row=quad*4+reg (m89-verified)
    #pragma unroll
    for (int i = 0; i < 4; ++i) {
        #pragma unroll
        for (int j = 0; j < 4; ++j) {
            const int col  = n0 + wn + j * 16 + rsel;
            const int rowb = m0 + wm + i * 16 + quad * 4;
            #pragma unroll
            for (int r = 0; r < 4; ++r) {
                const size_t off = (size_t)(rowb + r) * N + col;
                if (OUT_BF16) ((unsigned short*)Cp)[off] = f2bf(acc[i][j][r]);
                else          ((float*)Cp)[off] = acc[i][j][r];
            }
        }
    }
}

// ---------- gate + causal depthwise conv (L=3), running-window version ----------
// Each block: one batch b, CHUNK consecutive s rows, full D via 256 threads x 8.
// bx[s-1], bx[s-2] carried in registers across the s loop, so each BCx element
// is read exactly once (plus a 2-row halo per chunk).
__global__ __launch_bounds__(256)
void k_conv_gate(const unsigned short* __restrict__ BCx,
                 const float* __restrict__ conv_w,
                 unsigned short* __restrict__ y) {
    const int blk = blockIdx.x;
    const int b   = blk / (S_DIM / CHUNK);
    const int sc  = blk % (S_DIM / CHUNK);
    const int s0  = sc * CHUNK;
    const int d0  = threadIdx.x * 8;

    union U8 { uint4 v; unsigned short s[8]; };

    // conv weights for this thread's 8 channels
    float w0[8], w1[8], w2[8];
    #pragma unroll
    for (int j = 0; j < 8; ++j) {
        const float* w = conv_w + (size_t)(d0 + j) * 3;
        w0[j] = w[0]; w1[j] = w[1]; w2[j] = w[2];
    }

    float bxm1[8], bxm2[8];
    #pragma unroll
    for (int j = 0; j < 8; ++j) { bxm1[j] = 0.f; bxm2[j] = 0.f; }

    // halo: rows s0-1, s0-2 (block-uniform branch; only first chunk skips)
    if (s0 >= 1) {
        U8 g, xp;
        size_t rm1 = ((size_t)b * S_DIM + s0 - 1) * N1_DIM;
        g.v  = *(const uint4*)&BCx[rm1 + d0];
        xp.v = *(const uint4*)&BCx[rm1 + 2 * D_DIM + d0];
        #pragma unroll
        for (int j = 0; j < 8; ++j) bxm1[j] = bf2f(g.s[j]) * bf2f(xp.s[j]);
        size_t rm2 = ((size_t)b * S_DIM + s0 - 2) * N1_DIM;
        g.v  = *(const uint4*)&BCx[rm2 + d0];
        xp.v = *(const uint4*)&BCx[rm2 + 2 * D_DIM + d0];
        #pragma unroll
        for (int j = 0; j < 8; ++j) bxm2[j] = bf2f(g.s[j]) * bf2f(xp.s[j]);
    }

    size_t row = ((size_t)b * S_DIM + s0) * N1_DIM;
    size_t orow = ((size_t)b * S_DIM + s0) * D_DIM;
    for (int t = 0; t < CHUNK; ++t) {
        U8 g, xp, c;
        g.v  = *(const uint4*)&BCx[row + d0];
        xp.v = *(const uint4*)&BCx[row + 2 * D_DIM + d0];
        c.v  = *(const uint4*)&BCx[row + D_DIM + d0];
        U8 r;
        #pragma unroll
        for (int j = 0; j < 8; ++j) {
            const float bx0 = bf2f(g.s[j]) * bf2f(xp.s[j]);
            const float conv = w0[j] * bxm2[j] + w1[j] * bxm1[j] + w2[j] * bx0;
            r.s[j] = f2bf(bf2f(c.s[j]) * conv);
            bxm2[j] = bxm1[j];
            bxm1[j] = bx0;
        }
        *(uint4*)&y[orow + d0] = r.v;
        row  += N1_DIM;
        orow += D_DIM;
    }
}

extern "C" void kernel_launch(void* const* d_in, const int* in_sizes, int n_in,
                              void* d_out, int out_size, void* d_ws, size_t ws_size,
                              hipStream_t stream) {
    const float* x      = (const float*)d_in[0];   // (4,4096,2048)
    const float* W_in   = (const float*)d_in[1];   // (2048,6144)
    const float* conv_w = (const float*)d_in[2];   // (2048,3)
    const float* W_out  = (const float*)d_in[3];   // (2048,2048)
    float* out = (float*)d_out;

    // workspace layout (total ~302 MB):
    //   xb   : 16384x2048 bf16 = 64 MiB   (reused as y after GEMM1)
    //   Wt_in: 6144x2048 bf16  = 24 MiB
    //   Wt_out: 2048x2048 bf16 = 8 MiB
    //   BCx  : 16384x6144 bf16 = 192 MiB
    char* ws = (char*)d_ws;
    unsigned short* xb     = (unsigned short*)ws;
    unsigned short* Wt_in  = (unsigned short*)(ws + (size_t)67108864);
    unsigned short* Wt_out = (unsigned short*)(ws + (size_t)67108864 + 25165824);
    unsigned short* BCx    = (unsigned short*)(ws + (size_t)67108864 + 25165824 + 8388608);

    const int n8 = M_DIM * D_DIM / 8;
    k_convert<<<dim3((n8 + 255) / 256), 256, 0, stream>>>(x, xb, n8);
    k_transpose<<<dim3(N1_DIM / 32, D_DIM / 32), dim3(32, 8), 0, stream>>>(W_in, Wt_in, D_DIM, N1_DIM);
    k_transpose<<<dim3(D_DIM / 32, D_DIM / 32), dim3(32, 8), 0, stream>>>(W_out, Wt_out, D_DIM, D_DIM);

    k_gemm128<true><<<dim3(N1_DIM / 128, M_DIM / 128), 256, 0, stream>>>(xb, Wt_in, BCx, N1_DIM, D_DIM);
    k_conv_gate<<<dim3(B_DIM * S_DIM / CHUNK), 256, 0, stream>>>(BCx, conv_w, xb /* y overwrites xb */);
    k_gemm128<false><<<dim3(D_DIM / 128, M_DIM / 128), 256, 0, stream>>>(xb, Wt_out, out, D_DIM, D_DIM);
}

// Round 8
// 820.268 us; speedup vs baseline: 1.1154x; 1.1154x over previous
//
#include <hip/hip_runtime.h>
#include <cstddef>
#include <cstdint>

#define D_DIM 2048
#define S_DIM 4096
#define B_DIM 4
#define M_DIM (B_DIM * S_DIM)   // 16384
#define N1_DIM (3 * D_DIM)      // 6144
#define CHUNK 16                // s-rows per conv block

typedef short bf16x8 __attribute__((ext_vector_type(8)));
typedef float f32x4  __attribute__((ext_vector_type(4)));

typedef const unsigned int __attribute__((address_space(1))) gu32_t;
typedef unsigned int       __attribute__((address_space(3))) lu32_t;

__device__ __forceinline__ unsigned short f2bf(float f) {
    unsigned int u = __float_as_uint(f);
    u += 0x7FFFu + ((u >> 16) & 1u);   // round-to-nearest-even (finite inputs)
    return (unsigned short)(u >> 16);
}
__device__ __forceinline__ float bf2f(unsigned short h) {
    return __uint_as_float(((unsigned int)h) << 16);
}

// ---------- merged prep: fp32->bf16 convert of x  +  both weight transposes ----------
// Three independent jobs fused into one dispatch (block-uniform branch) to cut
// two launch/drain slots from the serial stream.
//   blocks [0, 16384)        : convert x (4.19M bf16x8 chunks, 256/block)
//   blocks [16384, 28672)    : transpose W_in  (2048x6144 -> 6144x2048)
//   blocks [28672, 32768)    : transpose W_out (2048x2048 -> 2048x2048)
__device__ __forceinline__ void prep_transpose(const float* __restrict__ in,
                                               unsigned short* __restrict__ out,
                                               int R, int C, int bx, int by, int tid) {
    __shared__ float t[32][33];
    const int x  = tid & 31;
    const int ty = tid >> 5;
    const int c0 = bx * 32, r0 = by * 32;
    for (int yy = ty; yy < 32; yy += 8)
        t[yy][x] = in[(size_t)(r0 + yy) * C + c0 + x];
    __syncthreads();
    for (int yy = ty; yy < 32; yy += 8)
        out[(size_t)(c0 + yy) * R + r0 + x] = f2bf(t[x][yy]);
}

__global__ __launch_bounds__(256)
void k_prep(const float* __restrict__ x, const float* __restrict__ W_in,
            const float* __restrict__ W_out, unsigned short* __restrict__ xb,
            unsigned short* __restrict__ Wt_in, unsigned short* __restrict__ Wt_out) {
    const int blk = blockIdx.x;
    const int tid = threadIdx.x;
    if (blk < 16384) {
        const int i = blk * 256 + tid;            // < 4194304 == M*D/8 exactly
        const float4* p = (const float4*)x + (size_t)i * 2;
        float4 a = p[0];
        float4 b = p[1];
        union { unsigned short s[8]; uint4 v; } r;
        r.s[0] = f2bf(a.x); r.s[1] = f2bf(a.y); r.s[2] = f2bf(a.z); r.s[3] = f2bf(a.w);
        r.s[4] = f2bf(b.x); r.s[5] = f2bf(b.y); r.s[6] = f2bf(b.z); r.s[7] = f2bf(b.w);
        ((uint4*)xb)[i] = r.v;
    } else if (blk < 28672) {
        const int b2 = blk - 16384;               // 12288 blocks: 192 x 64
        prep_transpose(W_in, Wt_in, D_DIM, N1_DIM, b2 % 192, b2 / 192, tid);
    } else {
        const int b3 = blk - 28672;               // 4096 blocks: 64 x 64
        prep_transpose(W_out, Wt_out, D_DIM, D_DIM, b3 % 64, b3 / 64, tid);
    }
}

// ---------- bf16 GEMM: C[M,N] = A[M,K] * Bt[N,K]^T (proven 128^2 kernel) ----------
// 128x128 tile, BK=64, 4 waves (2x2), each wave 64x64 via 4x4 of 16x16x32 MFMA.
// Staging: global_load_lds width=16, XOR-swizzled source granules so the
// contiguous LDS destination still yields conflict-free ds_read_b128.
// R6 lesson: NO XCD swizzle. The chunked remap made ~64 co-resident blocks
// per XCD span 24-32 MB of B-panels vs 4 MiB L2 -> B thrash (FETCH 537MB ->
// 1.56GB, dur 370 -> 463). Default dispatch's 537MB is already the structural
// floor: A-panels x 8 XCD L2s (512MB, L3-served) + B once (24MB).
template <bool OUT_BF16>
__global__ __launch_bounds__(256, 2)
void k_gemm128(const unsigned short* __restrict__ A, const unsigned short* __restrict__ Bt,
               void* __restrict__ Cp, int N, int K) {
    __shared__ unsigned short As[128 * 64];
    __shared__ unsigned short Bs[128 * 64];

    const int tid  = threadIdx.x;
    const int wave = tid >> 6;
    const int lane = tid & 63;
    const int m0 = blockIdx.y * 128;
    const int n0 = blockIdx.x * 128;
    const int wm = (wave & 1) * 64;
    const int wn = (wave >> 1) * 64;

    f32x4 acc[4][4] = {};

    const int srow = lane >> 3;
    const int gd   = lane & 7;
    const int quad = lane >> 4;
    const int rsel = lane & 15;

    const int KT = K >> 6;
    for (int kt = 0; kt < KT; ++kt) {
        const int k0 = kt << 6;
        __syncthreads();
        #pragma unroll
        for (int i = 0; i < 4; ++i) {
            const int seg = i * 4 + wave;
            const int row = seg * 8 + srow;
            const int gs  = gd ^ (row & 7);
            const unsigned short* ga = A  + (size_t)(m0 + row) * K + k0 + gs * 8;
            const unsigned short* gb = Bt + (size_t)(n0 + row) * K + k0 + gs * 8;
            __builtin_amdgcn_global_load_lds((gu32_t*)ga, (lu32_t*)(As + seg * 512), 16, 0, 0);
            __builtin_amdgcn_global_load_lds((gu32_t*)gb, (lu32_t*)(Bs + seg * 512), 16, 0, 0);
        }
        __syncthreads();

        #pragma unroll
        for (int kb = 0; kb < 2; ++kb) {
            bf16x8 af[4], bfr[4];
            #pragma unroll
            for (int i = 0; i < 4; ++i) {
                const int ra = wm + i * 16 + rsel;
                const int ga = (kb * 4 + quad) ^ (ra & 7);
                af[i] = *(const bf16x8*)&As[ra * 64 + ga * 8];
                const int rb = wn + i * 16 + rsel;
                const int gb = (kb * 4 + quad) ^ (rb & 7);
                bfr[i] = *(const bf16x8*)&Bs[rb * 64 + gb * 8];
            }
            #pragma unroll
            for (int i = 0; i < 4; ++i)
                #pragma unroll
                for (int j = 0; j < 4; ++j)
                    acc[i][j] = __builtin_amdgcn_mfma_f32_16x16x32_bf16(af[i], bfr[j], acc[i][j], 0, 0, 0);
        }
    }

    // Epilogue: C/D layout col=lane&15, row=quad*4+reg (m89-verified)
    #pragma unroll
    for (int i = 0; i < 4; ++i) {
        #pragma unroll
        for (int j = 0; j < 4; ++j) {
            const int col  = n0 + wn + j * 16 + rsel;
            const int rowb = m0 + wm + i * 16 + quad * 4;
            #pragma unroll
            for (int r = 0; r < 4; ++r) {
                const size_t off = (size_t)(rowb + r) * N + col;
                if (OUT_BF16) ((unsigned short*)Cp)[off] = f2bf(acc[i][j][r]);
                else          ((float*)Cp)[off] = acc[i][j][r];
            }
        }
    }
}

// ---------- gate + causal depthwise conv (L=3), running-window version ----------
// Each block: one batch b, CHUNK consecutive s rows, full D via 256 threads x 8.
// bx[s-1], bx[s-2] carried in registers across the s loop, so each BCx element
// is read exactly once (plus a 2-row halo per chunk).
__global__ __launch_bounds__(256)
void k_conv_gate(const unsigned short* __restrict__ BCx,
                 const float* __restrict__ conv_w,
                 unsigned short* __restrict__ y) {
    const int blk = blockIdx.x;
    const int b   = blk / (S_DIM / CHUNK);
    const int sc  = blk % (S_DIM / CHUNK);
    const int s0  = sc * CHUNK;
    const int d0  = threadIdx.x * 8;

    union U8 { uint4 v; unsigned short s[8]; };

    // conv weights for this thread's 8 channels
    float w0[8], w1[8], w2[8];
    #pragma unroll
    for (int j = 0; j < 8; ++j) {
        const float* w = conv_w + (size_t)(d0 + j) * 3;
        w0[j] = w[0]; w1[j] = w[1]; w2[j] = w[2];
    }

    float bxm1[8], bxm2[8];
    #pragma unroll
    for (int j = 0; j < 8; ++j) { bxm1[j] = 0.f; bxm2[j] = 0.f; }

    // halo: rows s0-1, s0-2 (block-uniform branch; only first chunk skips)
    if (s0 >= 1) {
        U8 g, xp;
        size_t rm1 = ((size_t)b * S_DIM + s0 - 1) * N1_DIM;
        g.v  = *(const uint4*)&BCx[rm1 + d0];
        xp.v = *(const uint4*)&BCx[rm1 + 2 * D_DIM + d0];
        #pragma unroll
        for (int j = 0; j < 8; ++j) bxm1[j] = bf2f(g.s[j]) * bf2f(xp.s[j]);
        size_t rm2 = ((size_t)b * S_DIM + s0 - 2) * N1_DIM;
        g.v  = *(const uint4*)&BCx[rm2 + d0];
        xp.v = *(const uint4*)&BCx[rm2 + 2 * D_DIM + d0];
        #pragma unroll
        for (int j = 0; j < 8; ++j) bxm2[j] = bf2f(g.s[j]) * bf2f(xp.s[j]);
    }

    size_t row = ((size_t)b * S_DIM + s0) * N1_DIM;
    size_t orow = ((size_t)b * S_DIM + s0) * D_DIM;
    for (int t = 0; t < CHUNK; ++t) {
        U8 g, xp, c;
        g.v  = *(const uint4*)&BCx[row + d0];
        xp.v = *(const uint4*)&BCx[row + 2 * D_DIM + d0];
        c.v  = *(const uint4*)&BCx[row + D_DIM + d0];
        U8 r;
        #pragma unroll
        for (int j = 0; j < 8; ++j) {
            const float bx0 = bf2f(g.s[j]) * bf2f(xp.s[j]);
            const float conv = w0[j] * bxm2[j] + w1[j] * bxm1[j] + w2[j] * bx0;
            r.s[j] = f2bf(bf2f(c.s[j]) * conv);
            bxm2[j] = bxm1[j];
            bxm1[j] = bx0;
        }
        *(uint4*)&y[orow + d0] = r.v;
        row  += N1_DIM;
        orow += D_DIM;
    }
}

extern "C" void kernel_launch(void* const* d_in, const int* in_sizes, int n_in,
                              void* d_out, int out_size, void* d_ws, size_t ws_size,
                              hipStream_t stream) {
    const float* x      = (const float*)d_in[0];   // (4,4096,2048)
    const float* W_in   = (const float*)d_in[1];   // (2048,6144)
    const float* conv_w = (const float*)d_in[2];   // (2048,3)
    const float* W_out  = (const float*)d_in[3];   // (2048,2048)
    float* out = (float*)d_out;

    // workspace layout (total ~302 MB):
    //   xb   : 16384x2048 bf16 = 64 MiB   (reused as y after GEMM1)
    //   Wt_in: 6144x2048 bf16  = 24 MiB
    //   Wt_out: 2048x2048 bf16 = 8 MiB
    //   BCx  : 16384x6144 bf16 = 192 MiB
    char* ws = (char*)d_ws;
    unsigned short* xb     = (unsigned short*)ws;
    unsigned short* Wt_in  = (unsigned short*)(ws + (size_t)67108864);
    unsigned short* Wt_out = (unsigned short*)(ws + (size_t)67108864 + 25165824);
    unsigned short* BCx    = (unsigned short*)(ws + (size_t)67108864 + 25165824 + 8388608);

    k_prep<<<dim3(32768), 256, 0, stream>>>(x, W_in, W_out, xb, Wt_in, Wt_out);

    k_gemm128<true><<<dim3(N1_DIM / 128, M_DIM / 128), 256, 0, stream>>>(xb, Wt_in, BCx, N1_DIM, D_DIM);
    k_conv_gate<<<dim3(B_DIM * S_DIM / CHUNK), 256, 0, stream>>>(BCx, conv_w, xb /* y overwrites xb */);
    k_gemm128<false><<<dim3(D_DIM / 128, M_DIM / 128), 256, 0, stream>>>(xb, Wt_out, out, D_DIM, D_DIM);
}